// Round 1
// baseline (333.953 us; speedup 1.0000x reference)
//
#include <hip/hip_runtime.h>

// ConvDeIndexer: fused sparse de-index + grouped ConvTranspose2d(512,256,k=4,s=4,g=8)
//
// Key identities:
//   stride==kernel => y[b, 32m+ocg, 4w+i, 4h+j] = sum_ic x[b,ic,w,h] * W[ic,ocg,i,j]
//   scattered x has <=8 nonzeros per (b,m,w,h): channel = ind + 64*m  (group == m)
//   override semantics: numpy C-order scatter, pos(k=0..3) then neg(k=0..3),
//   later write wins -> pair p is dead iff any later pair q>p has same index.
//
// Block = (b, m, w, i): 4*8*64*4 = 8192 blocks, 256 threads.
// Lanes along ocg so weight LDS reads are contiguous (conflict-free) and pair
// reads are broadcast. Thread (ocg, hsub) loops 8 hc -> 8 float4 outputs.

__global__ __launch_bounds__(256) void convdeidx_kernel(
    const int* __restrict__ ind_pos, const int* __restrict__ ind_neg,
    const float* __restrict__ val_pos, const float* __restrict__ val_neg,
    const float* __restrict__ weight, float* __restrict__ out)
{
    __shared__ float4 swt[2048];                 // [c*32+ocg] = W[64m+c][ocg][i][0..3], 32 KiB
    __shared__ __align__(16) int2 spair[64 * 10]; // [h*10 + p], p in [0,8): (c, bits(v)); stride 10 keeps 16B align

    const int bi  = blockIdx.x;
    const int i   = bi & 3;
    const int w   = (bi >> 2) & 63;
    const int m   = (bi >> 8) & 7;
    const int b   = bi >> 11;
    const int tid = threadIdx.x;

    // ---- stage (ind,val) pairs for all 64 h of this (b,m,w) ----
    {
        const int k = tid >> 6;                  // 0..3
        const int h = tid & 63;
        const int idx = (((b * 4 + k) * 8 + m) * 64 + w) * 64 + h;
        spair[h * 10 + k]     = make_int2(ind_pos[idx], __float_as_int(val_pos[idx]));
        spair[h * 10 + 4 + k] = make_int2(ind_neg[idx], __float_as_int(val_neg[idx]));
    }
    // ---- stage weight slice for (m, i): swt[c*32+ocg] ----
    {
        const float4* wsrc = (const float4*)weight;  // float4 idx: ((64m+c)*32+ocg)*4 + i
        #pragma unroll
        for (int r = 0; r < 8; ++r) {
            const int l = r * 256 + tid;             // l = c*32 + ocg, 0..2047
            swt[l] = wsrc[(size_t)(2048 * m + l) * 4 + i];
        }
    }
    __syncthreads();

    // ---- last-write-wins collision resolution (one thread per h) ----
    if (tid < 64) {
        int c[8];
        #pragma unroll
        for (int p = 0; p < 8; ++p) c[p] = spair[tid * 10 + p].x;
        #pragma unroll
        for (int p = 0; p < 7; ++p) {
            bool dead = false;
            #pragma unroll
            for (int q = p + 1; q < 8; ++q) dead |= (c[q] == c[p]);
            if (dead) spair[tid * 10 + p].y = 0;     // zero the value -> contributes nothing
        }
    }
    __syncthreads();

    const int ocg  = tid & 31;
    const int hsub = tid >> 5;                       // 0..7
    float* yrow = out + ((size_t)((b * 256 + m * 32 + ocg) * 256 + (w * 4 + i)) << 8);

    #pragma unroll
    for (int hc = 0; hc < 8; ++hc) {
        const int h = hc * 8 + hsub;
        const int4* pp = (const int4*)(spair + h * 10);  // 2 pairs per int4, 16B aligned
        float4 acc = make_float4(0.f, 0.f, 0.f, 0.f);
        #pragma unroll
        for (int pq = 0; pq < 4; ++pq) {
            const int4 two = pp[pq];
            const float  v0 = __int_as_float(two.y);
            const float  v1 = __int_as_float(two.w);
            const float4 w0 = swt[(two.x << 5) | ocg];
            const float4 w1 = swt[(two.z << 5) | ocg];
            acc.x += v0 * w0.x + v1 * w1.x;
            acc.y += v0 * w0.y + v1 * w1.y;
            acc.z += v0 * w0.z + v1 * w1.z;
            acc.w += v0 * w0.w + v1 * w1.w;
        }
        *reinterpret_cast<float4*>(yrow + 4 * h) = acc;  // ox = 4h..4h+3
    }
}

extern "C" void kernel_launch(void* const* d_in, const int* in_sizes, int n_in,
                              void* d_out, int out_size, void* d_ws, size_t ws_size,
                              hipStream_t stream) {
    const int*   ind_pos = (const int*)  d_in[0];
    const int*   ind_neg = (const int*)  d_in[1];
    const float* val_pos = (const float*)d_in[2];
    const float* val_neg = (const float*)d_in[3];
    const float* weight  = (const float*)d_in[4];
    float*       y       = (float*)d_out;

    hipLaunchKernelGGL(convdeidx_kernel, dim3(8192), dim3(256), 0, stream,
                       ind_pos, ind_neg, val_pos, val_neg, weight, y);
}

// Round 3
// 316.020 us; speedup vs baseline: 1.0567x; 1.0567x over previous
//
#include <hip/hip_runtime.h>

// ConvDeIndexer: fused sparse de-index + grouped ConvTranspose2d(512,256,k=4,s=4,g=8)
//
//   stride==kernel => y[b, 32m+ocg, 4w+i, 4h+j] = sum_ic x[b,ic,w,h] * W[ic,ocg,i,j]
//   scattered x has <=8 nonzeros per (b,m,w,h): channel = ind + 64*m (group == m)
//   override: numpy C-order scatter -> pair p dead iff any later pair q>p has same index
//
// Block = (b, m, w, i): 8192 blocks x 256 threads.
// Compute: lanes along ocg (weight LDS reads contiguous conflict-free, pair reads
// broadcast). Epilogue: acc[8] in regs -> XOR-swizzled LDS transpose (reusing the
// weight buffer) -> 1KiB-contiguous coalesced nontemporal wave-stores.

typedef float floatx4 __attribute__((ext_vector_type(4)));  // native vec4 for nontemporal store

__global__ __launch_bounds__(256) void convdeidx_kernel(
    const int* __restrict__ ind_pos, const int* __restrict__ ind_neg,
    const float* __restrict__ val_pos, const float* __restrict__ val_neg,
    const float* __restrict__ weight, float* __restrict__ out)
{
    __shared__ __align__(16) float4 swt[2048];    // weights, then reused as output transpose buffer
    __shared__ __align__(16) int2 spair[64 * 10]; // [h*10 + p], p in [0,8): (c, bits(v)); stride 10 keeps 16B align

    const int bi  = blockIdx.x;
    const int i   = bi & 3;
    const int w   = (bi >> 2) & 63;
    const int m   = (bi >> 8) & 7;
    const int b   = bi >> 11;
    const int tid = threadIdx.x;

    // ---- stage (ind,val) pairs for all 64 h of this (b,m,w) ----
    {
        const int k = tid >> 6;                  // 0..3
        const int h = tid & 63;
        const int idx = (((b * 4 + k) * 8 + m) * 64 + w) * 64 + h;
        spair[h * 10 + k]     = make_int2(ind_pos[idx], __float_as_int(val_pos[idx]));
        spair[h * 10 + 4 + k] = make_int2(ind_neg[idx], __float_as_int(val_neg[idx]));
    }
    // ---- stage weight slice for (m, i): swt[c*32+ocg] = W[64m+c][ocg][i][0..3] ----
    {
        const float4* wsrc = (const float4*)weight;  // float4 idx: ((64m+c)*32+ocg)*4 + i
        #pragma unroll
        for (int r = 0; r < 8; ++r) {
            const int l = r * 256 + tid;             // l = c*32 + ocg
            swt[l] = wsrc[(size_t)(2048 * m + l) * 4 + i];
        }
    }
    __syncthreads();

    // ---- last-write-wins collision resolution (one thread per h) ----
    if (tid < 64) {
        int c[8];
        #pragma unroll
        for (int p = 0; p < 8; ++p) c[p] = spair[tid * 10 + p].x;
        #pragma unroll
        for (int p = 0; p < 7; ++p) {
            bool dead = false;
            #pragma unroll
            for (int q = p + 1; q < 8; ++q) dead |= (c[q] == c[p]);
            if (dead) spair[tid * 10 + p].y = 0;     // zeroed value contributes nothing
        }
    }
    __syncthreads();

    const int ocg  = tid & 31;
    const int hsub = tid >> 5;                       // 0..7

    float4 acc[8];
    #pragma unroll
    for (int hc = 0; hc < 8; ++hc) {
        const int h = hc * 8 + hsub;
        const int4* pp = (const int4*)(spair + h * 10);  // 2 pairs per int4, 16B aligned
        float4 a = make_float4(0.f, 0.f, 0.f, 0.f);
        #pragma unroll
        for (int pq = 0; pq < 4; ++pq) {
            const int4 two = pp[pq];
            const float  v0 = __int_as_float(two.y);
            const float  v1 = __int_as_float(two.w);
            const float4 w0 = swt[(two.x << 5) | ocg];
            const float4 w1 = swt[(two.z << 5) | ocg];
            a.x += v0 * w0.x + v1 * w1.x;
            a.y += v0 * w0.y + v1 * w1.y;
            a.z += v0 * w0.z + v1 * w1.z;
            a.w += v0 * w0.w + v1 * w1.w;
        }
        acc[hc] = a;
    }

    // ---- transpose through LDS (reuse swt), then coalesced stores ----
    __syncthreads();                                  // all swt reads done
    #pragma unroll
    for (int hc = 0; hc < 8; ++hc) {
        const int h = hc * 8 + hsub;
        swt[(ocg << 6) | (h ^ (ocg & 7))] = acc[hc];  // XOR swizzle: 8 lanes/bank-group, conflict-free
    }
    __syncthreads();

    const int h2  = tid & 63;                         // float4 column within row (ox = 4*h2)
    const int ocq = tid >> 6;                         // 0..3
    const size_t oy = (size_t)(w * 4 + i);
    // float4 offset of (b, oc, oy, 0):
    size_t basef4 = ((((size_t)b * 256 + m * 32 + ocq) * 256 + oy) << 6);
    floatx4* outf4 = (floatx4*)out;
    #pragma unroll
    for (int r = 0; r < 8; ++r) {
        const int oc = r * 4 + ocq;                   // ocg' for this row
        const float4 v = swt[(oc << 6) | (h2 ^ (oc & 7))];
        floatx4 vv;
        vv.x = v.x; vv.y = v.y; vv.z = v.z; vv.w = v.w;
        __builtin_nontemporal_store(vv, outf4 + basef4 + h2);   // 1 KiB contiguous per wave
        basef4 += (size_t)4 * 256 * 64;               // advance 4 oc rows
    }
}

extern "C" void kernel_launch(void* const* d_in, const int* in_sizes, int n_in,
                              void* d_out, int out_size, void* d_ws, size_t ws_size,
                              hipStream_t stream) {
    const int*   ind_pos = (const int*)  d_in[0];
    const int*   ind_neg = (const int*)  d_in[1];
    const float* val_pos = (const float*)d_in[2];
    const float* val_neg = (const float*)d_in[3];
    const float* weight  = (const float*)d_in[4];
    float*       y       = (float*)d_out;

    hipLaunchKernelGGL(convdeidx_kernel, dim3(8192), dim3(256), 0, stream,
                       ind_pos, ind_neg, val_pos, val_neg, weight, y);
}

// Round 4
// 282.320 us; speedup vs baseline: 1.1829x; 1.1194x over previous
//
#include <hip/hip_runtime.h>

// ConvDeIndexer via densify + MFMA.
//   y[b, 32m+ocg, 4w+i, 4h+j] = sum_c X[c,h] * W[64m+c][ocg][i][j]   (per b,m,w)
// i.e. per (b,m,w): D[p,h] = sum_c Wt[p,c] * X[c,h],  p = ocg*16+i*4+j (M=512),
// h (N=64), c (K=64).  mfma_f32_16x16x32_bf16, A=Wt (m=p), B=X (n=h).
// C-layout: n=lane&15 (h), m=quad*4+reg -> quad=i, reg=j: each lane's 4 accs are
// one contiguous output float4 at (oc, oy=4w+i, ox=4h..4h+3). Direct stores.
//
// Kernel 1 pre-transposes weight f32[cin][p] -> bf16 ws[m][p][c] (2MB -> 512KB)
// so the main kernel stages A with contiguous copies. LDS rows padded to 72
// shorts (144B, 16B-aligned) -> uniform 8 lanes/bank = b128 conflict floor.
// Override semantics (numpy C-order scatter, later write wins) fall out free:
// one thread per h writes its 8 (pos k=0..3 then neg k=0..3) pairs in order.

typedef float f32x4  __attribute__((ext_vector_type(4)));
typedef short bf16x8 __attribute__((ext_vector_type(8)));

__device__ __forceinline__ unsigned short f32_to_bf16_rne(float f) {
    unsigned int u = __float_as_uint(f);
    return (unsigned short)((u + 0x7FFFu + ((u >> 16) & 1u)) >> 16);
}

// ---- Kernel 1: weight f32 [cin=512][p=512] -> bf16 ws[m=8][p=512][c=64] ----
__global__ __launch_bounds__(256) void wt_transpose_kernel(
    const float* __restrict__ weight, unsigned short* __restrict__ ws)
{
    __shared__ unsigned short stile[64 * 72];   // [p-local][c], stride 72
    const int m    = blockIdx.x >> 3;
    const int pblk = blockIdx.x & 7;
    const int t    = threadIdx.x;
    const int p    = t & 63;
    const int chi  = t >> 6;                    // 0..3
    #pragma unroll
    for (int r = 0; r < 16; ++r) {
        const int c = chi * 16 + r;
        const float v = weight[(size_t)(64 * m + c) * 512 + pblk * 64 + p]; // coalesced over p
        stile[p * 72 + c] = f32_to_bf16_rne(v);
    }
    __syncthreads();
    uint4* dst4 = (uint4*)(ws + (size_t)(m * 512 + pblk * 64) * 64);
    #pragma unroll
    for (int pass = 0; pass < 2; ++pass) {
        const int g = pass * 256 + t;           // granule 0..511 (64 rows x 8)
        const uint4 v = *(const uint4*)(stile + (g >> 3) * 72 + (g & 7) * 8);
        dst4[g] = v;                            // contiguous coalesced
    }
}

// ---- Kernel 2: main ----
__global__ __launch_bounds__(256) void convdeidx_mfma_kernel(
    const int* __restrict__ ind_pos, const int* __restrict__ ind_neg,
    const float* __restrict__ val_pos, const float* __restrict__ val_neg,
    const unsigned short* __restrict__ ws, float* __restrict__ out)
{
    __shared__ unsigned short sA[256 * 72];     // 36 KB: weight chunk, 256 p rows
    __shared__ unsigned short sX[64 * 72];      // 9 KB: densified X[h-row? no: [c? ] see below
    __shared__ int2 spair[64 * 10];             // (c, bits(v)) per (h, pair)

    // sX layout: [h][c] rows of 72 shorts? NO -- B operand needs 8 consecutive c
    // at fixed h: we store X transposed as [h][c] with c contiguous. (row = h)

    const int bi  = blockIdx.x;
    const int w   = bi & 63;
    const int m   = (bi >> 6) & 7;
    const int b   = bi >> 9;
    const int tid = threadIdx.x;
    const int wid = tid >> 6, lane = tid & 63;
    const int q   = lane >> 4, ln = lane & 15;  // quad, lane-in-16

    // stage (ind,val) pairs
    {
        const int k = tid >> 6, h = tid & 63;
        const int idx = (((b * 4 + k) * 8 + m) * 64 + w) * 64 + h;
        spair[h * 10 + k]     = make_int2(ind_pos[idx], __float_as_int(val_pos[idx]));
        spair[h * 10 + 4 + k] = make_int2(ind_neg[idx], __float_as_int(val_neg[idx]));
    }
    // zero sX (4608 shorts = 576 uint4)
    {
        uint4* x4 = (uint4*)sX;
        const uint4 z = make_uint4(0u, 0u, 0u, 0u);
        x4[tid] = z;
        x4[tid + 256] = z;
        if (tid < 64) x4[tid + 512] = z;
    }
    // stage A chunk 0: ws[m][0..255][c] -> sA rows (stride 72)
    const uint4* wsrc4 = (const uint4*)(ws + (size_t)m * 512 * 64);  // granule = 8 shorts
    #pragma unroll
    for (int r = 0; r < 8; ++r) {
        const int g = r * 256 + tid;            // 0..2047
        const uint4 v = wsrc4[g];
        *(uint4*)(sA + (g >> 3) * 72 + (g & 7) * 8) = v;
    }
    __syncthreads();

    // densify: thread h writes its 8 pairs in scatter order -> last write wins
    if (tid < 64) {
        const int h = tid;
        #pragma unroll
        for (int p = 0; p < 8; ++p) {
            const int2 pr = spair[h * 10 + p];
            sX[h * 72 + pr.x] = f32_to_bf16_rne(__int_as_float(pr.y));
        }
    }
    __syncthreads();

    f32x4* outv = (f32x4*)out;

    #pragma unroll
    for (int chunk = 0; chunk < 2; ++chunk) {
        if (chunk == 1) {
            __syncthreads();                     // chunk0 frag reads done
            #pragma unroll
            for (int r = 0; r < 8; ++r) {
                const int g = r * 256 + tid;
                const uint4 v = wsrc4[2048 + g];
                *(uint4*)(sA + (g >> 3) * 72 + (g & 7) * 8) = v;
            }
            __syncthreads();
        }

        f32x4 acc[4][4];
        #pragma unroll
        for (int mt = 0; mt < 4; ++mt)
            #pragma unroll
            for (int nt = 0; nt < 4; ++nt)
                acc[mt][nt] = (f32x4){0.f, 0.f, 0.f, 0.f};

        #pragma unroll
        for (int kt = 0; kt < 2; ++kt) {
            bf16x8 afr[4], bfr[4];
            #pragma unroll
            for (int mt = 0; mt < 4; ++mt)       // A[m=p][k=c]: row = wid*64+mt*16+ln
                afr[mt] = *(const bf16x8*)(sA + (wid * 64 + mt * 16 + ln) * 72 + (kt * 4 + q) * 8);
            #pragma unroll
            for (int nt = 0; nt < 4; ++nt)       // B[k=c][n=h]: stored [h][c], row = nt*16+ln
                bfr[nt] = *(const bf16x8*)(sX + (nt * 16 + ln) * 72 + (kt * 4 + q) * 8);
            #pragma unroll
            for (int mt = 0; mt < 4; ++mt)
                #pragma unroll
                for (int nt = 0; nt < 4; ++nt)
                    acc[mt][nt] = __builtin_amdgcn_mfma_f32_16x16x32_bf16(
                        afr[mt], bfr[nt], acc[mt][nt], 0, 0, 0);
        }

        // stores: p = chunk*256 + wid*64 + mt*16 + (q*4+reg)
        //   -> ocg = chunk*16 + wid*4 + mt, i = q, j = reg; h = nt*16 + ln
        const int ocg0 = chunk * 16 + wid * 4;
        #pragma unroll
        for (int mt = 0; mt < 4; ++mt) {
            const size_t rowbase =
                ((size_t)(b * 256 + m * 32 + ocg0 + mt) * 256 + (w * 4 + q)) * 64;
            #pragma unroll
            for (int nt = 0; nt < 4; ++nt)
                __builtin_nontemporal_store(acc[mt][nt], outv + rowbase + nt * 16 + ln);
        }
    }
}

extern "C" void kernel_launch(void* const* d_in, const int* in_sizes, int n_in,
                              void* d_out, int out_size, void* d_ws, size_t ws_size,
                              hipStream_t stream) {
    const int*   ind_pos = (const int*)  d_in[0];
    const int*   ind_neg = (const int*)  d_in[1];
    const float* val_pos = (const float*)d_in[2];
    const float* val_neg = (const float*)d_in[3];
    const float* weight  = (const float*)d_in[4];
    float*       y       = (float*)d_out;
    unsigned short* ws   = (unsigned short*)d_ws;   // needs 512 KB

    hipLaunchKernelGGL(wt_transpose_kernel, dim3(64), dim3(256), 0, stream, weight, ws);
    hipLaunchKernelGGL(convdeidx_mfma_kernel, dim3(2048), dim3(256), 0, stream,
                       ind_pos, ind_neg, val_pos, val_neg, ws, y);
}